// Round 1
// baseline (1186.164 us; speedup 1.0000x reference)
//
#include <hip/hip_runtime.h>
#include <math.h>

#define B_    4
#define C_    128
#define H_    96
#define W_    96
#define HW_   9216          // H*W
#define NPIX  36864         // B*HW
#define BHWC  4718592       // B*HW*C
#define BATCH_STRIDE 1179648 // HW*C

// ---------------- weight transposes ----------------
// wt: [k][c][oc]  from de_w [oc][c][k]   (9*128*128 = 147456)
// wo: [oc][k][c]  from off_w [oc][c][k]  (18*9*128  = 20736)
__global__ void k_transpose_w(const float* __restrict__ de_w,
                              const float* __restrict__ off_w,
                              float* __restrict__ wt, float* __restrict__ wo) {
  int i = blockIdx.x * 256 + threadIdx.x;
  if (i < 147456) {
    int oc = i & 127; int c = (i >> 7) & 127; int k = i >> 14;
    wt[i] = de_w[(oc * 128 + c) * 9 + k];
  }
  if (i < 20736) {
    int c = i & 127; int k = (i >> 7) % 9; int oc = i / 1152;
    wo[i] = off_w[(oc * 128 + c) * 9 + k];
  }
}

// ---------------- depthwise 3x3 + bias : NCHW in -> BHWC out ----------------
__global__ void k_dw(const float* __restrict__ x, const float* __restrict__ dw_w,
                     const float* __restrict__ dw_b, float* __restrict__ h1) {
  int i = blockIdx.x * 256 + threadIdx.x;   // NCHW order for coalesced reads
  if (i >= BHWC) return;
  int xx = i % 96; int yy = (i / 96) % 96; int c = (i / HW_) % 128; int b = i / BATCH_STRIDE;
  const float* xp = x + (b * 128 + c) * HW_;
  const float* wp = dw_w + c * 9;
  float acc = dw_b[c];
  #pragma unroll
  for (int dy = 0; dy < 3; ++dy) {
    int sy = yy + dy - 1;
    if (sy < 0 || sy >= 96) continue;
    #pragma unroll
    for (int dx = 0; dx < 3; ++dx) {
      int sx = xx + dx - 1;
      if (sx < 0 || sx >= 96) continue;
      acc += xp[sy * 96 + sx] * wp[dy * 3 + dx];
    }
  }
  h1[(b * HW_ + yy * 96 + xx) * 128 + c] = acc;
}

// ---------------- pointwise 1x1 + bias : BHWC -> BHWC ----------------
__global__ void k_pw(const float* __restrict__ h1, const float* __restrict__ pw_w,
                     const float* __restrict__ pw_b, float* __restrict__ s) {
  int i = blockIdx.x * 256 + threadIdx.x;   // channel-last order
  if (i >= BHWC) return;
  int oc = i & 127; int pix = i >> 7;
  const float4* hp = (const float4*)(h1 + pix * 128);
  const float4* wp = (const float4*)(pw_w + oc * 128);
  float acc = pw_b[oc];
  #pragma unroll 8
  for (int j = 0; j < 32; ++j) {
    float4 a = hp[j], w = wp[j];
    acc += a.x * w.x + a.y * w.y + a.z * w.z + a.w * w.w;
  }
  s[i] = acc;
}

// ---------------- InstanceNorm stats (per b,c over HW) ----------------
__global__ void k_instats(const float* __restrict__ s, float* __restrict__ ist) {
  int b = blockIdx.x / 36; int tile = blockIdx.x % 36;
  int c = threadIdx.x & 127; int half = threadIdx.x >> 7;
  const float* base = s + (size_t)(b * HW_ + tile * 256) * 128;
  float sum = 0.f, sq = 0.f;
  for (int p = half; p < 256; p += 2) {
    float v = base[p * 128 + c];
    sum += v; sq += v * v;
  }
  __shared__ float r1[256], r2[256];
  r1[threadIdx.x] = sum; r2[threadIdx.x] = sq;
  __syncthreads();
  if (half == 0) {
    atomicAdd(&ist[(b * 128 + c) * 2],     r1[c] + r1[c + 128]);
    atomicAdd(&ist[(b * 128 + c) * 2 + 1], r2[c] + r2[c + 128]);
  }
}

__global__ void k_infin(const float* __restrict__ ist, float* __restrict__ ifin) {
  int i = blockIdx.x * 256 + threadIdx.x;
  if (i >= 512) return;
  float mean = ist[2 * i] * (1.f / 9216.f);
  float var  = ist[2 * i + 1] * (1.f / 9216.f) - mean * mean;
  ifin[2 * i] = mean;
  ifin[2 * i + 1] = rsqrtf(var + 1e-5f);
}

// ---------------- apply IN + ReLU in place ----------------
__global__ void k_inapply(float* __restrict__ s, const float* __restrict__ ifin) {
  int i = blockIdx.x * 256 + threadIdx.x;
  if (i >= BHWC) return;
  int c = i & 127; int b = i / BATCH_STRIDE;
  float m = ifin[(b * 128 + c) * 2], r = ifin[(b * 128 + c) * 2 + 1];
  float v = (s[i] - m) * r;
  s[i] = v > 0.f ? v : 0.f;
}

// ---------------- offset conv 3x3 (128 -> 18) + bias ----------------
__global__ void k_off(const float* __restrict__ s, const float* __restrict__ wo,
                      const float* __restrict__ off_b, float* __restrict__ off) {
  int g = blockIdx.x * 256 + threadIdx.x;
  if (g >= NPIX * 18) return;
  int oc = g % 18; int pix = g / 18;
  int b = pix / HW_; int hw = pix % HW_; int y = hw / 96; int x = hw % 96;
  float acc = off_b[oc];
  for (int ky = 0; ky < 3; ++ky) {
    int sy = y + ky - 1; if (sy < 0 || sy >= 96) continue;
    for (int kx = 0; kx < 3; ++kx) {
      int sx = x + kx - 1; if (sx < 0 || sx >= 96) continue;
      const float4* sp = (const float4*)(s + (size_t)(b * HW_ + sy * 96 + sx) * 128);
      const float4* wp = (const float4*)(wo + (oc * 9 + ky * 3 + kx) * 128);
      #pragma unroll 8
      for (int j = 0; j < 32; ++j) {
        float4 a = sp[j], w = wp[j];
        acc += a.x * w.x + a.y * w.y + a.z * w.z + a.w * w.w;
      }
    }
  }
  off[pix * 18 + oc] = acc;
}

// ---------------- deformable conv: sample + einsum ----------------
// block: 256 threads, 32 pixels x 128 oc tile; thread does 4 oc x 4 pix.
__global__ __launch_bounds__(256) void k_deform(
    const float* __restrict__ s, const float* __restrict__ off,
    const float* __restrict__ wt, const float* __restrict__ de_b,
    float* __restrict__ d) {
  __shared__ float samp[128 * 32];   // [c][p], 16 KB
  int pixbase = blockIdx.x * 32;
  int tid = threadIdx.x;
  int to = tid & 31;    // oc = 4*to
  int tp = tid >> 5;    // p  = 4*tp (0..7)

  float acc[4][4];
  #pragma unroll
  for (int i = 0; i < 4; ++i)
    #pragma unroll
    for (int j = 0; j < 4; ++j) acc[i][j] = 0.f;

  // sampling-phase mapping: 8 threads per pixel, 16 channels each
  int pw_ = tid >> 3;       // pixel 0..31
  int l8  = tid & 7;        // channel group: c0 = l8*16
  int pix_s = pixbase + pw_;
  int b_s = pix_s / HW_; int hw_s = pix_s % HW_;
  int ys = hw_s / 96; int xs = hw_s % 96;
  const float* sb = s + (size_t)b_s * BATCH_STRIDE;

  for (int k = 0; k < 9; ++k) {
    // ---- sampling ----
    {
      float dy = off[pix_s * 18 + 2 * k];
      float dx = off[pix_s * 18 + 2 * k + 1];
      float py = (float)ys + (float)(k / 3 - 1) + dy;
      float px = (float)xs + (float)(k % 3 - 1) + dx;
      float y0f = floorf(py), x0f = floorf(px);
      float ly = py - y0f, lx = px - x0f;
      int y0 = (int)y0f, x0 = (int)x0f;
      bool vy0 = (y0 >= 0) && (y0 < 96), vy1 = (y0 + 1 >= 0) && (y0 + 1 < 96);
      bool vx0 = (x0 >= 0) && (x0 < 96), vx1 = (x0 + 1 >= 0) && (x0 + 1 < 96);
      float f00 = (vy0 && vx0) ? (1.f - ly) * (1.f - lx) : 0.f;
      float f01 = (vy0 && vx1) ? (1.f - ly) * lx : 0.f;
      float f10 = (vy1 && vx0) ? ly * (1.f - lx) : 0.f;
      float f11 = (vy1 && vx1) ? ly * lx : 0.f;
      int yc0 = min(max(y0, 0), 95), yc1 = min(max(y0 + 1, 0), 95);
      int xc0 = min(max(x0, 0), 95), xc1 = min(max(x0 + 1, 0), 95);
      const float* p00 = sb + (yc0 * 96 + xc0) * 128;
      const float* p01 = sb + (yc0 * 96 + xc1) * 128;
      const float* p10 = sb + (yc1 * 96 + xc0) * 128;
      const float* p11 = sb + (yc1 * 96 + xc1) * 128;
      int c0 = l8 * 16;
      #pragma unroll
      for (int j = 0; j < 4; ++j) {
        int c = c0 + 4 * j;
        float4 a  = *(const float4*)(p00 + c);
        float4 bq = *(const float4*)(p01 + c);
        float4 cq = *(const float4*)(p10 + c);
        float4 dq = *(const float4*)(p11 + c);
        samp[(c + 0) * 32 + pw_] = a.x * f00 + bq.x * f01 + cq.x * f10 + dq.x * f11;
        samp[(c + 1) * 32 + pw_] = a.y * f00 + bq.y * f01 + cq.y * f10 + dq.y * f11;
        samp[(c + 2) * 32 + pw_] = a.z * f00 + bq.z * f01 + cq.z * f10 + dq.z * f11;
        samp[(c + 3) * 32 + pw_] = a.w * f00 + bq.w * f01 + cq.w * f10 + dq.w * f11;
      }
    }
    __syncthreads();
    // ---- einsum: acc[oc4][p4] += wt[k][c][oc] * samp[c][p] ----
    const float4* wt4 = (const float4*)(wt + k * 128 * 128);
    #pragma unroll 4
    for (int c = 0; c < 128; ++c) {
      float4 w4 = wt4[c * 32 + to];
      float4 s4 = *(const float4*)(&samp[c * 32 + 4 * tp]);
      float wr[4] = {w4.x, w4.y, w4.z, w4.w};
      float sr[4] = {s4.x, s4.y, s4.z, s4.w};
      #pragma unroll
      for (int i = 0; i < 4; ++i)
        #pragma unroll
        for (int j = 0; j < 4; ++j)
          acc[i][j] = fmaf(wr[i], sr[j], acc[i][j]);
    }
    __syncthreads();
  }

  // write out + bias (channel-last d)
  float b0 = de_b[4 * to + 0], b1 = de_b[4 * to + 1],
        b2 = de_b[4 * to + 2], b3 = de_b[4 * to + 3];
  #pragma unroll
  for (int j = 0; j < 4; ++j) {
    int pix = pixbase + 4 * tp + j;
    float4 v = make_float4(acc[0][j] + b0, acc[1][j] + b1, acc[2][j] + b2, acc[3][j] + b3);
    *(float4*)(d + (size_t)pix * 128 + 4 * to) = v;
  }
}

// ---------------- GroupNorm(1,C) stats per b ----------------
__global__ void k_gnstats(const float* __restrict__ d, float* __restrict__ gst) {
  int b = blockIdx.x / 36; int tile = blockIdx.x % 36;
  const float* base = d + (size_t)b * BATCH_STRIDE + tile * 32768;
  float sum = 0.f, sq = 0.f;
  for (int p = threadIdx.x; p < 32768; p += 256) {
    float v = base[p]; sum += v; sq += v * v;
  }
  __shared__ float r1[256], r2[256];
  r1[threadIdx.x] = sum; r2[threadIdx.x] = sq;
  __syncthreads();
  for (int st = 128; st > 0; st >>= 1) {
    if (threadIdx.x < st) {
      r1[threadIdx.x] += r1[threadIdx.x + st];
      r2[threadIdx.x] += r2[threadIdx.x + st];
    }
    __syncthreads();
  }
  if (threadIdx.x == 0) {
    atomicAdd(&gst[b * 2],     r1[0]);
    atomicAdd(&gst[b * 2 + 1], r2[0]);
  }
}

__global__ void k_gnfin(const float* __restrict__ gst, float* __restrict__ gfin) {
  int b = threadIdx.x;
  if (b >= 4) return;
  const float invN = 1.f / (float)BATCH_STRIDE;
  float mean = gst[2 * b] * invN;
  float var  = gst[2 * b + 1] * invN - mean * mean;
  gfin[2 * b] = mean;
  gfin[2 * b + 1] = rsqrtf(var + 1e-5f);
}

// ---------------- final: GN affine + sigmoid gate, BHWC -> NCHW ----------------
__global__ void k_final(const float* __restrict__ d, const float* __restrict__ s,
                        const float* __restrict__ gfin, const float* __restrict__ gn_w,
                        const float* __restrict__ gn_b, float* __restrict__ out) {
  int i = blockIdx.x * 256 + threadIdx.x;   // NCHW order -> coalesced writes
  if (i >= BHWC) return;
  int xx = i % 96; int yy = (i / 96) % 96; int c = (i / HW_) % 128; int b = i / BATCH_STRIDE;
  size_t cl = (size_t)(b * HW_ + yy * 96 + xx) * 128 + c;
  float dv = d[cl], sv = s[cl];
  float dn = (dv - gfin[2 * b]) * gfin[2 * b + 1] * gn_w[c] + gn_b[c];
  float g = 1.f / (1.f + expf(-dn));
  out[i] = g * sv + sv;
}

extern "C" void kernel_launch(void* const* d_in, const int* in_sizes, int n_in,
                              void* d_out, int out_size, void* d_ws, size_t ws_size,
                              hipStream_t stream) {
  (void)in_sizes; (void)n_in; (void)out_size; (void)ws_size;
  const float* x     = (const float*)d_in[0];
  const float* dw_w  = (const float*)d_in[1];
  const float* dw_b  = (const float*)d_in[2];
  const float* pw_w  = (const float*)d_in[3];
  const float* pw_b  = (const float*)d_in[4];
  const float* off_w = (const float*)d_in[5];
  const float* off_b = (const float*)d_in[6];
  const float* de_w  = (const float*)d_in[7];
  const float* de_b  = (const float*)d_in[8];
  const float* gn_w  = (const float*)d_in[9];
  const float* gn_b  = (const float*)d_in[10];
  float* out = (float*)d_out;

  float* ws   = (float*)d_ws;
  float* h1   = ws;                 // BHWC depthwise out; reused as deform out
  float* s    = h1 + BHWC;          // BHWC shortcut
  float* off  = s + BHWC;           // [NPIX][18]
  float* wt   = off + NPIX * 18;    // [9][128][128]
  float* wo   = wt + 147456;        // [18][9][128]
  float* ist  = wo + 20736;         // [B][C][2] sum,sumsq
  float* ifin = ist + 1024;         // [B][C][2] mean,rstd
  float* gst  = ifin + 1024;        // [B][2]
  float* gfin = gst + 8;            // [B][2]

  // zero the atomic accumulators (ist..gfin region)
  hipMemsetAsync(ist, 0, (1024 + 1024 + 8 + 8) * sizeof(float), stream);

  k_transpose_w<<<576, 256, 0, stream>>>(de_w, off_w, wt, wo);
  k_dw<<<BHWC / 256, 256, 0, stream>>>(x, dw_w, dw_b, h1);
  k_pw<<<BHWC / 256, 256, 0, stream>>>(h1, pw_w, pw_b, s);
  k_instats<<<4 * 36, 256, 0, stream>>>(s, ist);
  k_infin<<<2, 256, 0, stream>>>(ist, ifin);
  k_inapply<<<BHWC / 256, 256, 0, stream>>>(s, ifin);
  k_off<<<(NPIX * 18 + 255) / 256, 256, 0, stream>>>(s, wo, off_b, off);
  k_deform<<<NPIX / 32, 256, 0, stream>>>(s, off, wt, de_b, h1);
  k_gnstats<<<4 * 36, 256, 0, stream>>>(h1, gst);
  k_gnfin<<<1, 64, 0, stream>>>(gst, gfin);
  k_final<<<BHWC / 256, 256, 0, stream>>>(h1, s, gfin, gn_w, gn_b, out);
}

// Round 2
// 925.801 us; speedup vs baseline: 1.2812x; 1.2812x over previous
//
#include <hip/hip_runtime.h>
#include <math.h>

#define B_    4
#define C_    128
#define H_    96
#define W_    96
#define HW_   9216          // H*W
#define NPIX  36864         // B*HW
#define BHWC  4718592       // B*HW*C
#define BATCH_STRIDE 1179648 // HW*C

// ---------------- weight transposes ----------------
// wt: [k][c][oc]      from de_w [oc][c][k]   (9*128*128 = 147456)
// wo: [k][c4][oc][4]  from off_w [oc][c][k]  (9*32*18*4 = 20736)
__global__ void k_transpose_w(const float* __restrict__ de_w,
                              const float* __restrict__ off_w,
                              float* __restrict__ wt, float* __restrict__ wo) {
  int i = blockIdx.x * 256 + threadIdx.x;
  if (i < 147456) {
    int oc = i & 127; int c = (i >> 7) & 127; int k = i >> 14;
    wt[i] = de_w[(oc * 128 + c) * 9 + k];
  }
  if (i < 20736) {
    int j  = i & 3;
    int oc = (i >> 2) % 18;
    int c4 = (i / 72) % 32;
    int k  = i / 2304;
    wo[i] = off_w[(oc * 128 + c4 * 4 + j) * 9 + k];
  }
}

// ---------------- depthwise 3x3 + bias : NCHW in -> BHWC out ----------------
__global__ void k_dw(const float* __restrict__ x, const float* __restrict__ dw_w,
                     const float* __restrict__ dw_b, float* __restrict__ h1) {
  int i = blockIdx.x * 256 + threadIdx.x;   // NCHW order for coalesced reads
  if (i >= BHWC) return;
  int xx = i % 96; int yy = (i / 96) % 96; int c = (i / HW_) % 128; int b = i / BATCH_STRIDE;
  const float* xp = x + (b * 128 + c) * HW_;
  const float* wp = dw_w + c * 9;
  float acc = dw_b[c];
  #pragma unroll
  for (int dy = 0; dy < 3; ++dy) {
    int sy = yy + dy - 1;
    if (sy < 0 || sy >= 96) continue;
    #pragma unroll
    for (int dx = 0; dx < 3; ++dx) {
      int sx = xx + dx - 1;
      if (sx < 0 || sx >= 96) continue;
      acc += xp[sy * 96 + sx] * wp[dy * 3 + dx];
    }
  }
  h1[(b * HW_ + yy * 96 + xx) * 128 + c] = acc;
}

// ---------------- pointwise 1x1 + bias : BHWC -> BHWC ----------------
__global__ void k_pw(const float* __restrict__ h1, const float* __restrict__ pw_w,
                     const float* __restrict__ pw_b, float* __restrict__ s) {
  int i = blockIdx.x * 256 + threadIdx.x;   // channel-last order
  if (i >= BHWC) return;
  int oc = i & 127; int pix = i >> 7;
  const float4* hp = (const float4*)(h1 + pix * 128);
  const float4* wp = (const float4*)(pw_w + oc * 128);
  float acc = pw_b[oc];
  #pragma unroll 8
  for (int j = 0; j < 32; ++j) {
    float4 a = hp[j], w = wp[j];
    acc += a.x * w.x + a.y * w.y + a.z * w.z + a.w * w.w;
  }
  s[i] = acc;
}

// ---------------- InstanceNorm stats (per b,c over HW) ----------------
__global__ void k_instats(const float* __restrict__ s, float* __restrict__ ist) {
  int b = blockIdx.x / 36; int tile = blockIdx.x % 36;
  int c = threadIdx.x & 127; int half = threadIdx.x >> 7;
  const float* base = s + (size_t)(b * HW_ + tile * 256) * 128;
  float sum = 0.f, sq = 0.f;
  for (int p = half; p < 256; p += 2) {
    float v = base[p * 128 + c];
    sum += v; sq += v * v;
  }
  __shared__ float r1[256], r2[256];
  r1[threadIdx.x] = sum; r2[threadIdx.x] = sq;
  __syncthreads();
  if (half == 0) {
    atomicAdd(&ist[(b * 128 + c) * 2],     r1[c] + r1[c + 128]);
    atomicAdd(&ist[(b * 128 + c) * 2 + 1], r2[c] + r2[c + 128]);
  }
}

__global__ void k_infin(const float* __restrict__ ist, float* __restrict__ ifin) {
  int i = blockIdx.x * 256 + threadIdx.x;
  if (i >= 512) return;
  float mean = ist[2 * i] * (1.f / 9216.f);
  float var  = ist[2 * i + 1] * (1.f / 9216.f) - mean * mean;
  ifin[2 * i] = mean;
  ifin[2 * i + 1] = rsqrtf(var + 1e-5f);
}

// ---------------- apply IN + ReLU in place ----------------
__global__ void k_inapply(float* __restrict__ s, const float* __restrict__ ifin) {
  int i = blockIdx.x * 256 + threadIdx.x;
  if (i >= BHWC) return;
  int c = i & 127; int b = i / BATCH_STRIDE;
  float m = ifin[(b * 128 + c) * 2], r = ifin[(b * 128 + c) * 2 + 1];
  float v = (s[i] - m) * r;
  s[i] = v > 0.f ? v : 0.f;
}

// ---------------- offset conv 3x3 (128 -> 18) + bias ----------------
// thread = pixel; 18 accumulators in VGPRs; window loaded once as float4;
// weights wo[k][c4][oc][4] indexed wave-uniformly -> scalar loads.
__global__ __launch_bounds__(256) void k_off(
    const float* __restrict__ s, const float* __restrict__ wo,
    const float* __restrict__ off_b, float* __restrict__ off) {
  int pix = blockIdx.x * 256 + threadIdx.x;
  int b = pix / HW_; int hw = pix % HW_; int y = hw / 96; int x = hw % 96;
  const float* sb = s + (size_t)b * BATCH_STRIDE;

  float acc[18];
  #pragma unroll
  for (int oc = 0; oc < 18; ++oc) acc[oc] = off_b[oc];

  for (int k = 0; k < 9; ++k) {
    int sy = y + k / 3 - 1;
    int sx = x + k % 3 - 1;
    if (sy < 0 || sy >= 96 || sx < 0 || sx >= 96) continue;
    const float4* win = (const float4*)(sb + (sy * 96 + sx) * 128);
    const float4* wk  = (const float4*)(wo + k * 2304);
    #pragma unroll 2
    for (int c4 = 0; c4 < 32; ++c4) {
      float4 a = win[c4];
      #pragma unroll
      for (int oc = 0; oc < 18; ++oc) {
        float4 w = wk[c4 * 18 + oc];
        acc[oc] = fmaf(a.x, w.x, acc[oc]);
        acc[oc] = fmaf(a.y, w.y, acc[oc]);
        acc[oc] = fmaf(a.z, w.z, acc[oc]);
        acc[oc] = fmaf(a.w, w.w, acc[oc]);
      }
    }
  }
  float* op = off + (size_t)pix * 18;
  #pragma unroll
  for (int oc = 0; oc < 18; ++oc) op[oc] = acc[oc];
}

// ---------------- deformable conv: sample + einsum ----------------
// block: 256 threads, 32 pixels x 128 oc tile; thread does 4 oc x 4 pix.
__global__ __launch_bounds__(256) void k_deform(
    const float* __restrict__ s, const float* __restrict__ off,
    const float* __restrict__ wt, const float* __restrict__ de_b,
    float* __restrict__ d) {
  __shared__ float samp[128 * 32];   // [c][p], 16 KB
  int pixbase = blockIdx.x * 32;
  int tid = threadIdx.x;
  int to = tid & 31;    // oc = 4*to
  int tp = tid >> 5;    // p  = 4*tp (0..7)

  float acc[4][4];
  #pragma unroll
  for (int i = 0; i < 4; ++i)
    #pragma unroll
    for (int j = 0; j < 4; ++j) acc[i][j] = 0.f;

  // sampling-phase mapping: 8 threads per pixel, 16 channels each
  int pw_ = tid >> 3;       // pixel 0..31
  int l8  = tid & 7;        // channel group: c0 = l8*16
  int pix_s = pixbase + pw_;
  int b_s = pix_s / HW_; int hw_s = pix_s % HW_;
  int ys = hw_s / 96; int xs = hw_s % 96;
  const float* sb = s + (size_t)b_s * BATCH_STRIDE;

  for (int k = 0; k < 9; ++k) {
    // ---- sampling ----
    {
      float dy = off[pix_s * 18 + 2 * k];
      float dx = off[pix_s * 18 + 2 * k + 1];
      float py = (float)ys + (float)(k / 3 - 1) + dy;
      float px = (float)xs + (float)(k % 3 - 1) + dx;
      float y0f = floorf(py), x0f = floorf(px);
      float ly = py - y0f, lx = px - x0f;
      int y0 = (int)y0f, x0 = (int)x0f;
      bool vy0 = (y0 >= 0) && (y0 < 96), vy1 = (y0 + 1 >= 0) && (y0 + 1 < 96);
      bool vx0 = (x0 >= 0) && (x0 < 96), vx1 = (x0 + 1 >= 0) && (x0 + 1 < 96);
      float f00 = (vy0 && vx0) ? (1.f - ly) * (1.f - lx) : 0.f;
      float f01 = (vy0 && vx1) ? (1.f - ly) * lx : 0.f;
      float f10 = (vy1 && vx0) ? ly * (1.f - lx) : 0.f;
      float f11 = (vy1 && vx1) ? ly * lx : 0.f;
      int yc0 = min(max(y0, 0), 95), yc1 = min(max(y0 + 1, 0), 95);
      int xc0 = min(max(x0, 0), 95), xc1 = min(max(x0 + 1, 0), 95);
      const float* p00 = sb + (yc0 * 96 + xc0) * 128;
      const float* p01 = sb + (yc0 * 96 + xc1) * 128;
      const float* p10 = sb + (yc1 * 96 + xc0) * 128;
      const float* p11 = sb + (yc1 * 96 + xc1) * 128;
      int c0 = l8 * 16;
      #pragma unroll
      for (int j = 0; j < 4; ++j) {
        int c = c0 + 4 * j;
        float4 a  = *(const float4*)(p00 + c);
        float4 bq = *(const float4*)(p01 + c);
        float4 cq = *(const float4*)(p10 + c);
        float4 dq = *(const float4*)(p11 + c);
        samp[(c + 0) * 32 + pw_] = a.x * f00 + bq.x * f01 + cq.x * f10 + dq.x * f11;
        samp[(c + 1) * 32 + pw_] = a.y * f00 + bq.y * f01 + cq.y * f10 + dq.y * f11;
        samp[(c + 2) * 32 + pw_] = a.z * f00 + bq.z * f01 + cq.z * f10 + dq.z * f11;
        samp[(c + 3) * 32 + pw_] = a.w * f00 + bq.w * f01 + cq.w * f10 + dq.w * f11;
      }
    }
    __syncthreads();
    // ---- einsum: acc[oc4][p4] += wt[k][c][oc] * samp[c][p] ----
    const float4* wt4 = (const float4*)(wt + k * 128 * 128);
    #pragma unroll 4
    for (int c = 0; c < 128; ++c) {
      float4 w4 = wt4[c * 32 + to];
      float4 s4 = *(const float4*)(&samp[c * 32 + 4 * tp]);
      float wr[4] = {w4.x, w4.y, w4.z, w4.w};
      float sr[4] = {s4.x, s4.y, s4.z, s4.w};
      #pragma unroll
      for (int i = 0; i < 4; ++i)
        #pragma unroll
        for (int j = 0; j < 4; ++j)
          acc[i][j] = fmaf(wr[i], sr[j], acc[i][j]);
    }
    __syncthreads();
  }

  // write out + bias (channel-last d)
  float b0 = de_b[4 * to + 0], b1 = de_b[4 * to + 1],
        b2 = de_b[4 * to + 2], b3 = de_b[4 * to + 3];
  #pragma unroll
  for (int j = 0; j < 4; ++j) {
    int pix = pixbase + 4 * tp + j;
    float4 v = make_float4(acc[0][j] + b0, acc[1][j] + b1, acc[2][j] + b2, acc[3][j] + b3);
    *(float4*)(d + (size_t)pix * 128 + 4 * to) = v;
  }
}

// ---------------- GroupNorm(1,C) stats per b ----------------
__global__ void k_gnstats(const float* __restrict__ d, float* __restrict__ gst) {
  int b = blockIdx.x / 36; int tile = blockIdx.x % 36;
  const float* base = d + (size_t)b * BATCH_STRIDE + tile * 32768;
  float sum = 0.f, sq = 0.f;
  for (int p = threadIdx.x; p < 32768; p += 256) {
    float v = base[p]; sum += v; sq += v * v;
  }
  __shared__ float r1[256], r2[256];
  r1[threadIdx.x] = sum; r2[threadIdx.x] = sq;
  __syncthreads();
  for (int st = 128; st > 0; st >>= 1) {
    if (threadIdx.x < st) {
      r1[threadIdx.x] += r1[threadIdx.x + st];
      r2[threadIdx.x] += r2[threadIdx.x + st];
    }
    __syncthreads();
  }
  if (threadIdx.x == 0) {
    atomicAdd(&gst[b * 2],     r1[0]);
    atomicAdd(&gst[b * 2 + 1], r2[0]);
  }
}

__global__ void k_gnfin(const float* __restrict__ gst, float* __restrict__ gfin) {
  int b = threadIdx.x;
  if (b >= 4) return;
  const float invN = 1.f / (float)BATCH_STRIDE;
  float mean = gst[2 * b] * invN;
  float var  = gst[2 * b + 1] * invN - mean * mean;
  gfin[2 * b] = mean;
  gfin[2 * b + 1] = rsqrtf(var + 1e-5f);
}

// ---------------- final: GN affine + sigmoid gate, BHWC -> NCHW ----------------
__global__ void k_final(const float* __restrict__ d, const float* __restrict__ s,
                        const float* __restrict__ gfin, const float* __restrict__ gn_w,
                        const float* __restrict__ gn_b, float* __restrict__ out) {
  int i = blockIdx.x * 256 + threadIdx.x;   // NCHW order -> coalesced writes
  if (i >= BHWC) return;
  int xx = i % 96; int yy = (i / 96) % 96; int c = (i / HW_) % 128; int b = i / BATCH_STRIDE;
  size_t cl = (size_t)(b * HW_ + yy * 96 + xx) * 128 + c;
  float dv = d[cl], sv = s[cl];
  float dn = (dv - gfin[2 * b]) * gfin[2 * b + 1] * gn_w[c] + gn_b[c];
  float g = 1.f / (1.f + expf(-dn));
  out[i] = g * sv + sv;
}

extern "C" void kernel_launch(void* const* d_in, const int* in_sizes, int n_in,
                              void* d_out, int out_size, void* d_ws, size_t ws_size,
                              hipStream_t stream) {
  (void)in_sizes; (void)n_in; (void)out_size; (void)ws_size;
  const float* x     = (const float*)d_in[0];
  const float* dw_w  = (const float*)d_in[1];
  const float* dw_b  = (const float*)d_in[2];
  const float* pw_w  = (const float*)d_in[3];
  const float* pw_b  = (const float*)d_in[4];
  const float* off_w = (const float*)d_in[5];
  const float* off_b = (const float*)d_in[6];
  const float* de_w  = (const float*)d_in[7];
  const float* de_b  = (const float*)d_in[8];
  const float* gn_w  = (const float*)d_in[9];
  const float* gn_b  = (const float*)d_in[10];
  float* out = (float*)d_out;

  float* ws   = (float*)d_ws;
  float* h1   = ws;                 // BHWC depthwise out; reused as deform out
  float* s    = h1 + BHWC;          // BHWC shortcut
  float* off  = s + BHWC;           // [NPIX][18]
  float* wt   = off + NPIX * 18;    // [9][128][128]
  float* wo   = wt + 147456;        // [9][32][18][4]
  float* ist  = wo + 20736;         // [B][C][2] sum,sumsq
  float* ifin = ist + 1024;         // [B][C][2] mean,rstd
  float* gst  = ifin + 1024;        // [B][2]
  float* gfin = gst + 8;            // [B][2]

  // zero the atomic accumulators (ist..gfin region)
  hipMemsetAsync(ist, 0, (1024 + 1024 + 8 + 8) * sizeof(float), stream);

  k_transpose_w<<<576, 256, 0, stream>>>(de_w, off_w, wt, wo);
  k_dw<<<BHWC / 256, 256, 0, stream>>>(x, dw_w, dw_b, h1);
  k_pw<<<BHWC / 256, 256, 0, stream>>>(h1, pw_w, pw_b, s);
  k_instats<<<4 * 36, 256, 0, stream>>>(s, ist);
  k_infin<<<2, 256, 0, stream>>>(ist, ifin);
  k_inapply<<<BHWC / 256, 256, 0, stream>>>(s, ifin);
  k_off<<<NPIX / 256, 256, 0, stream>>>(s, wo, off_b, off);
  k_deform<<<NPIX / 32, 256, 0, stream>>>(s, off, wt, de_b, h1);
  k_gnstats<<<4 * 36, 256, 0, stream>>>(h1, gst);
  k_gnfin<<<1, 64, 0, stream>>>(gst, gfin);
  k_final<<<BHWC / 256, 256, 0, stream>>>(h1, s, gfin, gn_w, gn_b, out);
}

// Round 3
// 622.726 us; speedup vs baseline: 1.9048x; 1.4867x over previous
//
#include <hip/hip_runtime.h>
#include <math.h>

#define B_    4
#define C_    128
#define H_    96
#define W_    96
#define HW_   9216          // H*W
#define NPIX  36864         // B*HW
#define BHWC  4718592       // B*HW*C
#define BATCH_STRIDE 1179648 // HW*C

// ---------------- weight transposes ----------------
// wt:  [k][c][oc]      from de_w [oc][c][k]   (9*128*128 = 147456)
// wo:  [k][c4][oc][4]  from off_w [oc][c][k]  (9*32*18*4 = 20736)
// pwt: [c][oc]         from pw_w [oc][c]      (16384)
__global__ void k_transpose_w(const float* __restrict__ de_w,
                              const float* __restrict__ off_w,
                              const float* __restrict__ pw_w,
                              float* __restrict__ wt, float* __restrict__ wo,
                              float* __restrict__ pwt) {
  int i = blockIdx.x * 256 + threadIdx.x;
  if (i < 147456) {
    int oc = i & 127; int c = (i >> 7) & 127; int k = i >> 14;
    wt[i] = de_w[(oc * 128 + c) * 9 + k];
  }
  if (i < 20736) {
    int j  = i & 3;
    int oc = (i >> 2) % 18;
    int c4 = (i / 72) % 32;
    int k  = i / 2304;
    wo[i] = off_w[(oc * 128 + c4 * 4 + j) * 9 + k];
  }
  if (i < 16384) {
    int oc = i & 127; int c = i >> 7;
    pwt[i] = pw_w[oc * 128 + c];
  }
}

// ---------------- depthwise 3x3 + bias : NCHW in -> NCHW out ----------------
__global__ void k_dw(const float* __restrict__ x, const float* __restrict__ dw_w,
                     const float* __restrict__ dw_b, float* __restrict__ h1) {
  int i = blockIdx.x * 256 + threadIdx.x;   // NCHW order, coalesced in AND out
  if (i >= BHWC) return;
  int xx = i % 96; int yy = (i / 96) % 96; int c = (i / HW_) % 128; int b = i / BATCH_STRIDE;
  const float* xp = x + (b * 128 + c) * HW_;
  const float* wp = dw_w + c * 9;
  float acc = dw_b[c];
  #pragma unroll
  for (int dy = 0; dy < 3; ++dy) {
    int sy = yy + dy - 1;
    if (sy < 0 || sy >= 96) continue;
    #pragma unroll
    for (int dx = 0; dx < 3; ++dx) {
      int sx = xx + dx - 1;
      if (sx < 0 || sx >= 96) continue;
      acc += xp[sy * 96 + sx] * wp[dy * 3 + dx];
    }
  }
  h1[i] = acc;
}

// ---------------- pointwise 1x1 + bias : NCHW in -> BHWC out ----------------
// tiled GEMM: block = 32 pixels x 128 oc, thread = 4 oc x 4 pix.
__global__ __launch_bounds__(256) void k_pw(
    const float* __restrict__ h1, const float* __restrict__ pwt,
    const float* __restrict__ pw_b, float* __restrict__ s) {
  __shared__ float samp[32 * 128];   // [p4][c][4], 16 KB
  int tid = threadIdx.x;
  int pixbase = blockIdx.x * 32;
  int b = pixbase / HW_;
  int hw0 = pixbase % HW_;

  // stage: thread (=c row) copies 32 contiguous pixels from NCHW h1
  if (tid < 128) {
    const float* hp = h1 + (size_t)(b * 128 + tid) * HW_ + hw0;
    #pragma unroll
    for (int p4 = 0; p4 < 8; ++p4) {
      float4 v = *(const float4*)(hp + p4 * 4);
      *(float4*)&samp[p4 * 512 + tid * 4] = v;   // lane-contiguous 16B: no conflicts
    }
  }
  __syncthreads();

  int to = tid & 31;    // oc = 4*to
  int tp = tid >> 5;    // pixel group p4 = tp
  float acc[4][4];
  #pragma unroll
  for (int i = 0; i < 4; ++i)
    #pragma unroll
    for (int j = 0; j < 4; ++j) acc[i][j] = 0.f;

  const float4* wp4 = (const float4*)pwt;
  const float4* sp4 = (const float4*)&samp[tp * 512];
  #pragma unroll 8
  for (int c = 0; c < 128; ++c) {
    float4 w4 = wp4[c * 32 + to];   // coalesced 512B across 32 lanes, L1-hot
    float4 s4 = sp4[c];             // broadcast, conflict-free
    float wr[4] = {w4.x, w4.y, w4.z, w4.w};
    float sr[4] = {s4.x, s4.y, s4.z, s4.w};
    #pragma unroll
    for (int i = 0; i < 4; ++i)
      #pragma unroll
      for (int j = 0; j < 4; ++j)
        acc[i][j] = fmaf(wr[i], sr[j], acc[i][j]);
  }

  float b0 = pw_b[4 * to + 0], b1 = pw_b[4 * to + 1],
        b2 = pw_b[4 * to + 2], b3 = pw_b[4 * to + 3];
  #pragma unroll
  for (int j = 0; j < 4; ++j) {
    int pix = pixbase + 4 * tp + j;
    float4 v = make_float4(acc[0][j] + b0, acc[1][j] + b1, acc[2][j] + b2, acc[3][j] + b3);
    *(float4*)(s + (size_t)pix * 128 + 4 * to) = v;
  }
}

// ---------------- InstanceNorm stats (per b,c over HW) ----------------
__global__ void k_instats(const float* __restrict__ s, float* __restrict__ ist) {
  int b = blockIdx.x / 36; int tile = blockIdx.x % 36;
  int c = threadIdx.x & 127; int half = threadIdx.x >> 7;
  const float* base = s + (size_t)(b * HW_ + tile * 256) * 128;
  float sum = 0.f, sq = 0.f;
  for (int p = half; p < 256; p += 2) {
    float v = base[p * 128 + c];
    sum += v; sq += v * v;
  }
  __shared__ float r1[256], r2[256];
  r1[threadIdx.x] = sum; r2[threadIdx.x] = sq;
  __syncthreads();
  if (half == 0) {
    atomicAdd(&ist[(b * 128 + c) * 2],     r1[c] + r1[c + 128]);
    atomicAdd(&ist[(b * 128 + c) * 2 + 1], r2[c] + r2[c + 128]);
  }
}

__global__ void k_infin(const float* __restrict__ ist, float* __restrict__ ifin) {
  int i = blockIdx.x * 256 + threadIdx.x;
  if (i >= 512) return;
  float mean = ist[2 * i] * (1.f / 9216.f);
  float var  = ist[2 * i + 1] * (1.f / 9216.f) - mean * mean;
  ifin[2 * i] = mean;
  ifin[2 * i + 1] = rsqrtf(var + 1e-5f);
}

// ---------------- apply IN + ReLU in place ----------------
__global__ void k_inapply(float* __restrict__ s, const float* __restrict__ ifin) {
  int i = blockIdx.x * 256 + threadIdx.x;
  if (i >= BHWC) return;
  int c = i & 127; int b = i / BATCH_STRIDE;
  float m = ifin[(b * 128 + c) * 2], r = ifin[(b * 128 + c) * 2 + 1];
  float v = (s[i] - m) * r;
  s[i] = v > 0.f ? v : 0.f;
}

// ---------------- offset conv 3x3 (128 -> 18) + bias ----------------
// thread = pixel; 18 accumulators in VGPRs; window loaded once as float4;
// weights wo[k][c4][oc][4] indexed wave-uniformly -> scalar loads.
__global__ __launch_bounds__(256) void k_off(
    const float* __restrict__ s, const float* __restrict__ wo,
    const float* __restrict__ off_b, float* __restrict__ off) {
  int pix = blockIdx.x * 256 + threadIdx.x;
  int b = pix / HW_; int hw = pix % HW_; int y = hw / 96; int x = hw % 96;
  const float* sb = s + (size_t)b * BATCH_STRIDE;

  float acc[18];
  #pragma unroll
  for (int oc = 0; oc < 18; ++oc) acc[oc] = off_b[oc];

  for (int k = 0; k < 9; ++k) {
    int sy = y + k / 3 - 1;
    int sx = x + k % 3 - 1;
    if (sy < 0 || sy >= 96 || sx < 0 || sx >= 96) continue;
    const float4* win = (const float4*)(sb + (sy * 96 + sx) * 128);
    const float4* wk  = (const float4*)(wo + k * 2304);
    #pragma unroll 2
    for (int c4 = 0; c4 < 32; ++c4) {
      float4 a = win[c4];
      #pragma unroll
      for (int oc = 0; oc < 18; ++oc) {
        float4 w = wk[c4 * 18 + oc];
        acc[oc] = fmaf(a.x, w.x, acc[oc]);
        acc[oc] = fmaf(a.y, w.y, acc[oc]);
        acc[oc] = fmaf(a.z, w.z, acc[oc]);
        acc[oc] = fmaf(a.w, w.w, acc[oc]);
      }
    }
  }
  float* op = off + (size_t)pix * 18;
  #pragma unroll
  for (int oc = 0; oc < 18; ++oc) op[oc] = acc[oc];
}

// ---------------- deformable conv: sample + einsum ----------------
// block: 256 threads, 32 pixels x 128 oc tile; thread does 4 oc x 4 pix.
__global__ __launch_bounds__(256) void k_deform(
    const float* __restrict__ s, const float* __restrict__ off,
    const float* __restrict__ wt, const float* __restrict__ de_b,
    float* __restrict__ d) {
  __shared__ float samp[128 * 32];   // [c][p], 16 KB
  int pixbase = blockIdx.x * 32;
  int tid = threadIdx.x;
  int to = tid & 31;    // oc = 4*to
  int tp = tid >> 5;    // p  = 4*tp (0..7)

  float acc[4][4];
  #pragma unroll
  for (int i = 0; i < 4; ++i)
    #pragma unroll
    for (int j = 0; j < 4; ++j) acc[i][j] = 0.f;

  // sampling-phase mapping: 8 threads per pixel, 16 channels each
  int pw_ = tid >> 3;       // pixel 0..31
  int l8  = tid & 7;        // channel group: c0 = l8*16
  int pix_s = pixbase + pw_;
  int b_s = pix_s / HW_; int hw_s = pix_s % HW_;
  int ys = hw_s / 96; int xs = hw_s % 96;
  const float* sb = s + (size_t)b_s * BATCH_STRIDE;

  for (int k = 0; k < 9; ++k) {
    // ---- sampling ----
    {
      float dy = off[pix_s * 18 + 2 * k];
      float dx = off[pix_s * 18 + 2 * k + 1];
      float py = (float)ys + (float)(k / 3 - 1) + dy;
      float px = (float)xs + (float)(k % 3 - 1) + dx;
      float y0f = floorf(py), x0f = floorf(px);
      float ly = py - y0f, lx = px - x0f;
      int y0 = (int)y0f, x0 = (int)x0f;
      bool vy0 = (y0 >= 0) && (y0 < 96), vy1 = (y0 + 1 >= 0) && (y0 + 1 < 96);
      bool vx0 = (x0 >= 0) && (x0 < 96), vx1 = (x0 + 1 >= 0) && (x0 + 1 < 96);
      float f00 = (vy0 && vx0) ? (1.f - ly) * (1.f - lx) : 0.f;
      float f01 = (vy0 && vx1) ? (1.f - ly) * lx : 0.f;
      float f10 = (vy1 && vx0) ? ly * (1.f - lx) : 0.f;
      float f11 = (vy1 && vx1) ? ly * lx : 0.f;
      int yc0 = min(max(y0, 0), 95), yc1 = min(max(y0 + 1, 0), 95);
      int xc0 = min(max(x0, 0), 95), xc1 = min(max(x0 + 1, 0), 95);
      const float* p00 = sb + (yc0 * 96 + xc0) * 128;
      const float* p01 = sb + (yc0 * 96 + xc1) * 128;
      const float* p10 = sb + (yc1 * 96 + xc0) * 128;
      const float* p11 = sb + (yc1 * 96 + xc1) * 128;
      int c0 = l8 * 16;
      #pragma unroll
      for (int j = 0; j < 4; ++j) {
        int c = c0 + 4 * j;
        float4 a  = *(const float4*)(p00 + c);
        float4 bq = *(const float4*)(p01 + c);
        float4 cq = *(const float4*)(p10 + c);
        float4 dq = *(const float4*)(p11 + c);
        samp[(c + 0) * 32 + pw_] = a.x * f00 + bq.x * f01 + cq.x * f10 + dq.x * f11;
        samp[(c + 1) * 32 + pw_] = a.y * f00 + bq.y * f01 + cq.y * f10 + dq.y * f11;
        samp[(c + 2) * 32 + pw_] = a.z * f00 + bq.z * f01 + cq.z * f10 + dq.z * f11;
        samp[(c + 3) * 32 + pw_] = a.w * f00 + bq.w * f01 + cq.w * f10 + dq.w * f11;
      }
    }
    __syncthreads();
    // ---- einsum: acc[oc4][p4] += wt[k][c][oc] * samp[c][p] ----
    const float4* wt4 = (const float4*)(wt + k * 128 * 128);
    #pragma unroll 4
    for (int c = 0; c < 128; ++c) {
      float4 w4 = wt4[c * 32 + to];
      float4 s4 = *(const float4*)(&samp[c * 32 + 4 * tp]);
      float wr[4] = {w4.x, w4.y, w4.z, w4.w};
      float sr[4] = {s4.x, s4.y, s4.z, s4.w};
      #pragma unroll
      for (int i = 0; i < 4; ++i)
        #pragma unroll
        for (int j = 0; j < 4; ++j)
          acc[i][j] = fmaf(wr[i], sr[j], acc[i][j]);
    }
    __syncthreads();
  }

  // write out + bias (channel-last d)
  float b0 = de_b[4 * to + 0], b1 = de_b[4 * to + 1],
        b2 = de_b[4 * to + 2], b3 = de_b[4 * to + 3];
  #pragma unroll
  for (int j = 0; j < 4; ++j) {
    int pix = pixbase + 4 * tp + j;
    float4 v = make_float4(acc[0][j] + b0, acc[1][j] + b1, acc[2][j] + b2, acc[3][j] + b3);
    *(float4*)(d + (size_t)pix * 128 + 4 * to) = v;
  }
}

// ---------------- GroupNorm(1,C) stats per b ----------------
__global__ void k_gnstats(const float* __restrict__ d, float* __restrict__ gst) {
  int b = blockIdx.x / 36; int tile = blockIdx.x % 36;
  const float* base = d + (size_t)b * BATCH_STRIDE + tile * 32768;
  float sum = 0.f, sq = 0.f;
  for (int p = threadIdx.x; p < 32768; p += 256) {
    float v = base[p]; sum += v; sq += v * v;
  }
  __shared__ float r1[256], r2[256];
  r1[threadIdx.x] = sum; r2[threadIdx.x] = sq;
  __syncthreads();
  for (int st = 128; st > 0; st >>= 1) {
    if (threadIdx.x < st) {
      r1[threadIdx.x] += r1[threadIdx.x + st];
      r2[threadIdx.x] += r2[threadIdx.x + st];
    }
    __syncthreads();
  }
  if (threadIdx.x == 0) {
    atomicAdd(&gst[b * 2],     r1[0]);
    atomicAdd(&gst[b * 2 + 1], r2[0]);
  }
}

__global__ void k_gnfin(const float* __restrict__ gst, float* __restrict__ gfin) {
  int b = threadIdx.x;
  if (b >= 4) return;
  const float invN = 1.f / (float)BATCH_STRIDE;
  float mean = gst[2 * b] * invN;
  float var  = gst[2 * b + 1] * invN - mean * mean;
  gfin[2 * b] = mean;
  gfin[2 * b + 1] = rsqrtf(var + 1e-5f);
}

// ---------------- final: GN affine + sigmoid gate, BHWC -> NCHW ----------------
__global__ void k_final(const float* __restrict__ d, const float* __restrict__ s,
                        const float* __restrict__ gfin, const float* __restrict__ gn_w,
                        const float* __restrict__ gn_b, float* __restrict__ out) {
  int i = blockIdx.x * 256 + threadIdx.x;   // NCHW order -> coalesced writes
  if (i >= BHWC) return;
  int xx = i % 96; int yy = (i / 96) % 96; int c = (i / HW_) % 128; int b = i / BATCH_STRIDE;
  size_t cl = (size_t)(b * HW_ + yy * 96 + xx) * 128 + c;
  float dv = d[cl], sv = s[cl];
  float dn = (dv - gfin[2 * b]) * gfin[2 * b + 1] * gn_w[c] + gn_b[c];
  float g = 1.f / (1.f + expf(-dn));
  out[i] = g * sv + sv;
}

extern "C" void kernel_launch(void* const* d_in, const int* in_sizes, int n_in,
                              void* d_out, int out_size, void* d_ws, size_t ws_size,
                              hipStream_t stream) {
  (void)in_sizes; (void)n_in; (void)out_size; (void)ws_size;
  const float* x     = (const float*)d_in[0];
  const float* dw_w  = (const float*)d_in[1];
  const float* dw_b  = (const float*)d_in[2];
  const float* pw_w  = (const float*)d_in[3];
  const float* pw_b  = (const float*)d_in[4];
  const float* off_w = (const float*)d_in[5];
  const float* off_b = (const float*)d_in[6];
  const float* de_w  = (const float*)d_in[7];
  const float* de_b  = (const float*)d_in[8];
  const float* gn_w  = (const float*)d_in[9];
  const float* gn_b  = (const float*)d_in[10];
  float* out = (float*)d_out;

  float* ws   = (float*)d_ws;
  float* h1   = ws;                 // NCHW depthwise out; reused as deform out (BHWC)
  float* s    = h1 + BHWC;          // BHWC shortcut
  float* off  = s + BHWC;           // [NPIX][18]
  float* wt   = off + NPIX * 18;    // [9][128][128]
  float* wo   = wt + 147456;        // [9][32][18][4]
  float* pwt  = wo + 20736;         // [c][oc] 16384
  float* ist  = pwt + 16384;        // [B][C][2] sum,sumsq
  float* ifin = ist + 1024;         // [B][C][2] mean,rstd
  float* gst  = ifin + 1024;        // [B][2]
  float* gfin = gst + 8;            // [B][2]

  // zero the atomic accumulators (ist..gfin region)
  hipMemsetAsync(ist, 0, (1024 + 1024 + 8 + 8) * sizeof(float), stream);

  k_transpose_w<<<576, 256, 0, stream>>>(de_w, off_w, pw_w, wt, wo, pwt);
  k_dw<<<BHWC / 256, 256, 0, stream>>>(x, dw_w, dw_b, h1);
  k_pw<<<NPIX / 32, 256, 0, stream>>>(h1, pwt, pw_b, s);
  k_instats<<<4 * 36, 256, 0, stream>>>(s, ist);
  k_infin<<<2, 256, 0, stream>>>(ist, ifin);
  k_inapply<<<BHWC / 256, 256, 0, stream>>>(s, ifin);
  k_off<<<NPIX / 256, 256, 0, stream>>>(s, wo, off_b, off);
  k_deform<<<NPIX / 32, 256, 0, stream>>>(s, off, wt, de_b, h1);
  k_gnstats<<<4 * 36, 256, 0, stream>>>(h1, gst);
  k_gnfin<<<1, 64, 0, stream>>>(gst, gfin);
  k_final<<<BHWC / 256, 256, 0, stream>>>(h1, s, gfin, gn_w, gn_b, out);
}